// Round 16
// baseline (1253.600 us; speedup 1.0000x reference)
//
#include <hip/hip_runtime.h>

// Batched QP via FISTA on the dual, Q = I (reference hardcodes eye(64)).
//
// R16 = consolidation: R9 skeleton (best measured: 1360us rocprof) + the
// R11 wins WITHOUT the pins (R15 showed pins cost 60us: VGPR 32->36,
// occupancy 91->68, dur 1420). Allocator verdict after 3 failed taming
// attempts (waves_per_eu, restructure, asm pins): hipcc parks loop-carried
// A-arrays in AGPRs regardless of budget; accept it.
// Deltas vs R9: (1) early-exit probe machinery deleted (never fires — the
// Frobenius eta is ~20x conservative); (2) eta*b folded into yb0 (-1 VALU/
// iter); (3) iteration 199 peeled (kills per-iter cmp+cndmask); (4) FOUR
// independent FMA chains per matvec (was 2) — v_fmac dep latency ~4cy left
// issue gaps at <8 waves/SIMD; free fix.

constexpr double csqrt_(double x) {
  double g = x * 0.5 + 0.5;
  for (int i = 0; i < 40; ++i) g = 0.5 * (g + x / g);
  return g;
}
struct CoefT { float c[200]; };
constexpr CoefT make_coefs() {
  CoefT T{};
  double t = 1.0;
  for (int k = 0; k < 200; ++k) {
    double tn = 0.5 * (1.0 + csqrt_(1.0 + 4.0 * t * t));
    T.c[k] = (float)((t - 1.0) / tn);
    t = tn;
  }
  return T;
}
__device__ constexpr CoefT kCoef = make_coefs();

__device__ __forceinline__ float dpp_add_xor1(float v) {
  int r = __builtin_amdgcn_update_dpp(0, __float_as_int(v), 0xB1, 0xF, 0xF, true);
  return v + __int_as_float(r);
}
__device__ __forceinline__ float dpp_add_xor2(float v) {
  int r = __builtin_amdgcn_update_dpp(0, __float_as_int(v), 0x4E, 0xF, 0xF, true);
  return v + __int_as_float(r);
}
__device__ __forceinline__ float swz_add_xor4(float v) {
  int r = __builtin_amdgcn_ds_swizzle(__float_as_int(v), 0x101F);
  return v + __int_as_float(r);
}

__global__ __launch_bounds__(512)
void qp_fista_kernel(const float* __restrict__ A,
                     const float* __restrict__ x,
                     const float* __restrict__ b,
                     float* __restrict__ out) {
  const int batch = blockIdx.x;
  const int tid = threadIdx.x;
  const int w = tid >> 6;   // wave 0..7

  __shared__ __align__(16) float tile[8192];  // A staging; later overlaid

  const float* Ag = A + (size_t)batch * 8192;

  // ---- stage A into LDS, coalesced float4 ----
  {
    const float4* Ag4 = (const float4*)Ag;
    float4* t4 = (float4*)tile;
#pragma unroll
    for (int k = 0; k < 4; ++k) t4[tid + k * 512] = Ag4[tid + k * 512];
  }
  __syncthreads();

  // ---- register views (16 + 16 floats per thread) ----
  const int r  = tid >> 2;  // mv2: row owned
  const int cq = tid & 3;   // mv2: col-quarter (quad lane bits 0-1)
  float Ar[16];
  {
    const float4* t4 = (const float4*)tile;
#pragma unroll
    for (int j = 0; j < 4; ++j) {
      float4 v = t4[r * 16 + cq * 4 + j];
      Ar[4 * j + 0] = v.x; Ar[4 * j + 1] = v.y;
      Ar[4 * j + 2] = v.z; Ar[4 * j + 3] = v.w;
    }
  }
  const int c  = tid >> 3;  // mv1: col owned
  const int rq = tid & 7;   // mv1: row-eighth (lane bits 0-2)
  float Ac[16];
#pragma unroll
  for (int i = 0; i < 16; ++i) Ac[i] = tile[(rq * 16 + i) * 64 + c];

  // sum of squares (Ar covers each A element exactly once across 512 threads)
  float ss = 0.f;
#pragma unroll
  for (int i = 0; i < 16; ++i) ss = fmaf(Ar[i], Ar[i], ss);
#pragma unroll
  for (int d = 1; d < 64; d <<= 1) ss += __shfl_xor(ss, d, 64);  // one-time

  __syncthreads();  // register extraction done; overlay small buffers

  float* zbuf = tile;         // 4 sections x 20 dw (z[0..63]); banks 0/20/8/28
  float* ybuf = tile + 96;    // 8 sections x 20 dw (y[0..127]); 8 distinct banks
  float* wsb  = tile + 272;   // 8 per-wave sum-of-squares

  if ((tid & 63) == 0) wsb[w] = ss;
  const float breg = b[(size_t)batch * 128 + r];
  const float xreg = x[(size_t)batch * 64 + c];
  if (rq == 0) zbuf[(c >> 4) * 20 + (c & 15)] = xreg;  // z0 = primal(0) = x
  __syncthreads();

  float sum8 = 0.f;
#pragma unroll
  for (int i = 0; i < 8; ++i) sum8 += wsb[i];
  const float eta = 1.0f / fmaxf(8.0f * sum8, 1e-12f);  // ||Qinv||_F = 8
  const float yb0 = eta * breg;  // folded: y + eta*(acc-b) = fma(eta,acc,y-yb0)

  const float4* zs = (const float4*)(zbuf + cq * 20);
  const float4* ys = (const float4*)(ybuf + rq * 20);
  float* ywr = ybuf + w * 20 + (r & 15);               // r>>4 == w
  float* zwr = zbuf + (c >> 4) * 20 + (c & 15);

  float lam = 0.f, y = 0.f;

#pragma unroll 1
  for (int it = 0; it < 199; ++it) {
    const float coef = kCoef.c[it];

    // ---- mv2: (Az)[r], 4 independent FMA chains ----
    float p0 = 0.f, p1 = 0.f, p2 = 0.f, p3 = 0.f;
#pragma unroll
    for (int j = 0; j < 4; ++j) {
      float4 zz = zs[j];
      p0 = fmaf(Ar[4 * j + 0], zz.x, p0);
      p1 = fmaf(Ar[4 * j + 1], zz.y, p1);
      p2 = fmaf(Ar[4 * j + 2], zz.z, p2);
      p3 = fmaf(Ar[4 * j + 3], zz.w, p3);
    }
    float acc = (p0 + p1) + (p2 + p3);
    acc = dpp_add_xor1(acc);
    acc = dpp_add_xor2(acc);           // full row dot, replicated in quad
    float ln = fmaxf(0.f, fmaf(eta, acc, y - yb0));
    float yn = fmaf(coef, ln - lam, ln);
    lam = ln; y = yn;
    if (cq == 0) *ywr = yn;
    __syncthreads();  // ybuf ready

    // ---- mv1: (A^T y)[c], 4 independent FMA chains ----
    float q0 = 0.f, q1 = 0.f, q2 = 0.f, q3 = 0.f;
#pragma unroll
    for (int j = 0; j < 4; ++j) {
      float4 yy = ys[j];
      q0 = fmaf(Ac[4 * j + 0], yy.x, q0);
      q1 = fmaf(Ac[4 * j + 1], yy.y, q1);
      q2 = fmaf(Ac[4 * j + 2], yy.z, q2);
      q3 = fmaf(Ac[4 * j + 3], yy.w, q3);
    }
    float s = (q0 + q1) + (q2 + q3);
    s = dpp_add_xor1(s);
    s = dpp_add_xor2(s);
    s = swz_add_xor4(s);               // full col dot over 8 lanes
    if (rq == 0) *zwr = xreg - s;      // z = x - A^T y
    __syncthreads();
  }

  // ---- peeled it = 199: write lam, final primal ----
  {
    float p0 = 0.f, p1 = 0.f, p2 = 0.f, p3 = 0.f;
#pragma unroll
    for (int j = 0; j < 4; ++j) {
      float4 zz = zs[j];
      p0 = fmaf(Ar[4 * j + 0], zz.x, p0);
      p1 = fmaf(Ar[4 * j + 1], zz.y, p1);
      p2 = fmaf(Ar[4 * j + 2], zz.z, p2);
      p3 = fmaf(Ar[4 * j + 3], zz.w, p3);
    }
    float acc = (p0 + p1) + (p2 + p3);
    acc = dpp_add_xor1(acc);
    acc = dpp_add_xor2(acc);
    float ln = fmaxf(0.f, fmaf(eta, acc, y - yb0));
    if (cq == 0) *ywr = ln;            // final lambda
    __syncthreads();

    float q0 = 0.f, q1 = 0.f, q2 = 0.f, q3 = 0.f;
#pragma unroll
    for (int j = 0; j < 4; ++j) {
      float4 yy = ys[j];
      q0 = fmaf(Ac[4 * j + 0], yy.x, q0);
      q1 = fmaf(Ac[4 * j + 1], yy.y, q1);
      q2 = fmaf(Ac[4 * j + 2], yy.z, q2);
      q3 = fmaf(Ac[4 * j + 3], yy.w, q3);
    }
    float s = (q0 + q1) + (q2 + q3);
    s = dpp_add_xor1(s);
    s = dpp_add_xor2(s);
    s = swz_add_xor4(s);
    if (rq == 0) *zwr = xreg - s;      // z* = x - A^T lam
    __syncthreads();
  }

  if (tid < 64) {
    out[(size_t)batch * 64 + tid] = zbuf[(tid >> 4) * 20 + (tid & 15)];
  }
}

extern "C" void kernel_launch(void* const* d_in, const int* in_sizes, int n_in,
                              void* d_out, int out_size, void* d_ws, size_t ws_size,
                              hipStream_t stream) {
  // setup_inputs order: Q (ignored: identity), A, x, b
  const float* A = (const float*)d_in[1];
  const float* x = (const float*)d_in[2];
  const float* b = (const float*)d_in[3];
  float* out = (float*)d_out;
  qp_fista_kernel<<<dim3(8192), dim3(512), 0, stream>>>(A, x, b, out);
}

// Round 17
// 1037.227 us; speedup vs baseline: 1.2086x; 1.2086x over previous
//
#include <hip/hip_runtime.h>

// Batched QP via FISTA on the dual, Q = I (reference hardcodes eye(64)).
//
// R17 = R9 EXACT skeleton + register-neutral wins only.
// Evidence ledger: R9 best (rocprof 1360us, VGPR 32, occ 91%). R15 pins:
// VGPR 36, occ 68%, 1420 (lost). R16 4-chains: VGPR 40, occ 68%, 1470
// (lost). Every arch-VGPR increase beyond 32 costs 2 waves/SIMD and nets
// negative. VALUBusy cross-check (R7 930us busy @1823 vs R9 1047us @1360)
// shows it's a utilization %, not an inst-count proxy — the proven lever
// was LDS/cross-lane reduction (R7->R9 via DPP/swizzle, -463us).
// Deltas vs R9 (all register-neutral):
//  (1) early-exit probe deleted: eta is ~175x below 1/L (Frobenius bound),
//      trajectory never goes bitwise-stationary in 200 iters -> pure cost.
//  (2) eta*b folded into yb0 (-1 VALU/iter).
//  (3) it=199 peeled (kills per-iter (it==199)?: cmp+cndmask).
// Keep: TWO FMA chains/phase (R9-proven), no pins, 512 thr, stride-20 LDS.

constexpr double csqrt_(double x) {
  double g = x * 0.5 + 0.5;
  for (int i = 0; i < 40; ++i) g = 0.5 * (g + x / g);
  return g;
}
struct CoefT { float c[200]; };
constexpr CoefT make_coefs() {
  CoefT T{};
  double t = 1.0;
  for (int k = 0; k < 200; ++k) {
    double tn = 0.5 * (1.0 + csqrt_(1.0 + 4.0 * t * t));
    T.c[k] = (float)((t - 1.0) / tn);
    t = tn;
  }
  return T;
}
__device__ constexpr CoefT kCoef = make_coefs();

__device__ __forceinline__ float dpp_add_xor1(float v) {
  int r = __builtin_amdgcn_update_dpp(0, __float_as_int(v), 0xB1, 0xF, 0xF, true);
  return v + __int_as_float(r);
}
__device__ __forceinline__ float dpp_add_xor2(float v) {
  int r = __builtin_amdgcn_update_dpp(0, __float_as_int(v), 0x4E, 0xF, 0xF, true);
  return v + __int_as_float(r);
}
__device__ __forceinline__ float swz_add_xor4(float v) {
  int r = __builtin_amdgcn_ds_swizzle(__float_as_int(v), 0x101F);
  return v + __int_as_float(r);
}

__global__ __launch_bounds__(512)
void qp_fista_kernel(const float* __restrict__ A,
                     const float* __restrict__ x,
                     const float* __restrict__ b,
                     float* __restrict__ out) {
  const int batch = blockIdx.x;
  const int tid = threadIdx.x;
  const int w = tid >> 6;   // wave 0..7

  __shared__ __align__(16) float tile[8192];  // A staging; later overlaid

  const float* Ag = A + (size_t)batch * 8192;

  // ---- stage A into LDS, coalesced float4 ----
  {
    const float4* Ag4 = (const float4*)Ag;
    float4* t4 = (float4*)tile;
#pragma unroll
    for (int k = 0; k < 4; ++k) t4[tid + k * 512] = Ag4[tid + k * 512];
  }
  __syncthreads();

  // ---- register views (16 + 16 floats per thread) ----
  const int r  = tid >> 2;  // mv2: row owned
  const int cq = tid & 3;   // mv2: col-quarter (quad lane bits 0-1)
  float Ar[16];
  {
    const float4* t4 = (const float4*)tile;
#pragma unroll
    for (int j = 0; j < 4; ++j) {
      float4 v = t4[r * 16 + cq * 4 + j];
      Ar[4 * j + 0] = v.x; Ar[4 * j + 1] = v.y;
      Ar[4 * j + 2] = v.z; Ar[4 * j + 3] = v.w;
    }
  }
  const int c  = tid >> 3;  // mv1: col owned
  const int rq = tid & 7;   // mv1: row-eighth (lane bits 0-2)
  float Ac[16];
#pragma unroll
  for (int i = 0; i < 16; ++i) Ac[i] = tile[(rq * 16 + i) * 64 + c];

  // sum of squares (Ar covers each A element exactly once across 512 threads)
  float ss = 0.f;
#pragma unroll
  for (int i = 0; i < 16; ++i) ss = fmaf(Ar[i], Ar[i], ss);
#pragma unroll
  for (int d = 1; d < 64; d <<= 1) ss += __shfl_xor(ss, d, 64);  // one-time

  __syncthreads();  // register extraction done; overlay small buffers

  float* zbuf = tile;         // 4 sections x 20 dw (z[0..63]); banks 0/20/8/28
  float* ybuf = tile + 96;    // 8 sections x 20 dw (y[0..127]); 8 distinct banks
  float* wsb  = tile + 272;   // 8 per-wave sum-of-squares

  if ((tid & 63) == 0) wsb[w] = ss;
  const float breg = b[(size_t)batch * 128 + r];
  const float xreg = x[(size_t)batch * 64 + c];
  if (rq == 0) zbuf[(c >> 4) * 20 + (c & 15)] = xreg;  // z0 = primal(0) = x
  __syncthreads();

  float sum8 = 0.f;
#pragma unroll
  for (int i = 0; i < 8; ++i) sum8 += wsb[i];
  const float eta = 1.0f / fmaxf(8.0f * sum8, 1e-12f);  // ||Qinv||_F = 8
  const float yb0 = eta * breg;  // folded: y + eta*(acc-b) = fma(eta,acc,y-yb0)

  const float4* zs = (const float4*)(zbuf + cq * 20);
  const float4* ys = (const float4*)(ybuf + rq * 20);
  float* ywr = ybuf + w * 20 + (r & 15);               // r>>4 == w
  float* zwr = zbuf + (c >> 4) * 20 + (c & 15);

  float lam = 0.f, y = 0.f;

#pragma unroll 1
  for (int it = 0; it < 199; ++it) {
    const float coef = kCoef.c[it];

    // ---- mv2: (Az)[r], 2 chains (R9-proven) ----
    float p0 = 0.f, p1 = 0.f;
#pragma unroll
    for (int j = 0; j < 4; ++j) {
      float4 zz = zs[j];
      p0 = fmaf(Ar[4 * j + 0], zz.x, p0);
      p1 = fmaf(Ar[4 * j + 1], zz.y, p1);
      p0 = fmaf(Ar[4 * j + 2], zz.z, p0);
      p1 = fmaf(Ar[4 * j + 3], zz.w, p1);
    }
    float acc = p0 + p1;
    acc = dpp_add_xor1(acc);
    acc = dpp_add_xor2(acc);           // full row dot, replicated in quad
    float ln = fmaxf(0.f, fmaf(eta, acc, y - yb0));
    float yn = fmaf(coef, ln - lam, ln);
    lam = ln; y = yn;
    if (cq == 0) *ywr = yn;
    __syncthreads();  // ybuf ready

    // ---- mv1: (A^T y)[c], 2 chains ----
    float q0 = 0.f, q1 = 0.f;
#pragma unroll
    for (int j = 0; j < 4; ++j) {
      float4 yy = ys[j];
      q0 = fmaf(Ac[4 * j + 0], yy.x, q0);
      q1 = fmaf(Ac[4 * j + 1], yy.y, q1);
      q0 = fmaf(Ac[4 * j + 2], yy.z, q0);
      q1 = fmaf(Ac[4 * j + 3], yy.w, q1);
    }
    float s = q0 + q1;
    s = dpp_add_xor1(s);
    s = dpp_add_xor2(s);
    s = swz_add_xor4(s);               // full col dot over 8 lanes
    if (rq == 0) *zwr = xreg - s;      // z = x - A^T y
    __syncthreads();
  }

  // ---- peeled it = 199: write lam, final primal ----
  {
    float p0 = 0.f, p1 = 0.f;
#pragma unroll
    for (int j = 0; j < 4; ++j) {
      float4 zz = zs[j];
      p0 = fmaf(Ar[4 * j + 0], zz.x, p0);
      p1 = fmaf(Ar[4 * j + 1], zz.y, p1);
      p0 = fmaf(Ar[4 * j + 2], zz.z, p0);
      p1 = fmaf(Ar[4 * j + 3], zz.w, p1);
    }
    float acc = p0 + p1;
    acc = dpp_add_xor1(acc);
    acc = dpp_add_xor2(acc);
    float ln = fmaxf(0.f, fmaf(eta, acc, y - yb0));
    if (cq == 0) *ywr = ln;            // final lambda
    __syncthreads();

    float q0 = 0.f, q1 = 0.f;
#pragma unroll
    for (int j = 0; j < 4; ++j) {
      float4 yy = ys[j];
      q0 = fmaf(Ac[4 * j + 0], yy.x, q0);
      q1 = fmaf(Ac[4 * j + 1], yy.y, q1);
      q0 = fmaf(Ac[4 * j + 2], yy.z, q0);
      q1 = fmaf(Ac[4 * j + 3], yy.w, q1);
    }
    float s = q0 + q1;
    s = dpp_add_xor1(s);
    s = dpp_add_xor2(s);
    s = swz_add_xor4(s);
    if (rq == 0) *zwr = xreg - s;      // z* = x - A^T lam
    __syncthreads();
  }

  if (tid < 64) {
    out[(size_t)batch * 64 + tid] = zbuf[(tid >> 4) * 20 + (tid & 15)];
  }
}

extern "C" void kernel_launch(void* const* d_in, const int* in_sizes, int n_in,
                              void* d_out, int out_size, void* d_ws, size_t ws_size,
                              hipStream_t stream) {
  // setup_inputs order: Q (ignored: identity), A, x, b
  const float* A = (const float*)d_in[1];
  const float* x = (const float*)d_in[2];
  const float* b = (const float*)d_in[3];
  float* out = (float*)d_out;
  qp_fista_kernel<<<dim3(8192), dim3(512), 0, stream>>>(A, x, b, out);
}